// Round 6
// baseline (1111.966 us; speedup 1.0000x reference)
//
#include <hip/hip_runtime.h>
#include <hip/hip_fp16.h>
#include <stdint.h>

// ---------------------------------------------------------------------------
// Problem geometry (all compile-time):
//   x: (64, 48, 512, 2, 2) fp32. seq[s,n,f] = x[n, f>>2, 8*s, (f>>1)&1, f&1]
//   (only batch rows n<64 of the 512 matter downstream).
//   Layer1 BiGRU: in=192, H=256, 64 steps. Layer2 BiGRU: in=512, H=256.
//   Only final hiddens of layer2 used. dec_h = w_adj @ [hf,hb] + b_adj.
//   Decoder GRU (in=56, H=256) 6 steps, out = w_fc1@h + b_fc1 -> (64,6,56).
//
// ROUNDS 2-5 LESSON: hipcc will not keep >~100 long-lived per-thread dwords
// in registers across the step loop (observed targets 84/128/256 + scratch
// spills at 6-132MB; VGPR pins and explicit AGPR asm both spilled around).
// ALSO: fdot2 consumes weights at 128B/cyc/wave while L2 and LDS each supply
// ~128B/cyc/CU -> fully-streamed matvec is only ~2x slower than resident.
// Strategy: HYBRID. Hold 72 weight dwords resident (safely under the 128
// budget), stream the rest from L2 every step; idle thread-half prefetches
// next step's gi into LDS. Decoder: 4 chains/block, fully streamed weights
// (each loaded u32 reused 4x), no residency fight at all.
// ---------------------------------------------------------------------------

#define HD 256
#define G3 768
#define NSEQ 64
#define NSTEP 64

typedef _Float16 hvec2 __attribute__((ext_vector_type(2)));

__device__ __forceinline__ float sigmf(float x) {
    return 1.0f / (1.0f + __expf(-x));
}

#if __has_builtin(__builtin_amdgcn_fdot2)
__device__ __forceinline__ float fdot2u(uint32_t w, uint32_t h, float acc) {
    return __builtin_amdgcn_fdot2(__builtin_bit_cast(hvec2, w),
                                  __builtin_bit_cast(hvec2, h), acc, false);
}
#else
__device__ __forceinline__ float fdot2u(uint32_t w, uint32_t h, float acc) {
    const __half2 wv = __builtin_bit_cast(__half2, w);
    const __half2 hv = __builtin_bit_cast(__half2, h);
    acc += __half2float(wv.x) * __half2float(hv.x);
    acc += __half2float(wv.y) * __half2float(hv.y);
    return acc;
}
#endif

__device__ __forceinline__ uint32_t pkh(float a, float b) {
    uint32_t lo = __half_as_ushort(__float2half_rn(a));
    uint32_t hi = __half_as_ushort(__float2half_rn(b));
    return lo | (hi << 16);
}

#define L6(X) X(0) X(1) X(2) X(3) X(4) X(5)

// resident chunks: 6 per gate row (of 16 per k-half) = 18 uint4 = 72 dwords
#define LRES(i) \
    const uint4 wr##i = wbase[(i) * G3]; \
    const uint4 wz##i = wbase[(i) * G3 + 256]; \
    const uint4 wn##i = wbase[(i) * G3 + 512];

#define DRES(i) { \
    const uint4 hp = *(const uint4*)&hb[hoff + 4 * (i)]; \
    ar0 = fdot2u(wr##i.x, hp.x, ar0); ar1 = fdot2u(wr##i.y, hp.y, ar1); \
    ar0 = fdot2u(wr##i.z, hp.z, ar0); ar1 = fdot2u(wr##i.w, hp.w, ar1); \
    az0 = fdot2u(wz##i.x, hp.x, az0); az1 = fdot2u(wz##i.y, hp.y, az1); \
    az0 = fdot2u(wz##i.z, hp.z, az0); az1 = fdot2u(wz##i.w, hp.w, az1); \
    an0 = fdot2u(wn##i.x, hp.x, an0); an1 = fdot2u(wn##i.y, hp.y, an1); \
    an0 = fdot2u(wn##i.z, hp.z, an0); an1 = fdot2u(wn##i.w, hp.w, an1); }

// ---------------- weight prep ----------------
// Repack Whh (768x256 fp32) -> uint4[q*768 + j], q=0..31: k=8q..8q+7 of row j.
__global__ __launch_bounds__(256) void pack_whhT(
    const float* __restrict__ w0, const float* __restrict__ w1,
    const float* __restrict__ w2, const float* __restrict__ w3,
    const float* __restrict__ w4,
    uint32_t* __restrict__ o0, uint32_t* __restrict__ o1,
    uint32_t* __restrict__ o2, uint32_t* __restrict__ o3,
    uint32_t* __restrict__ o4)
{
    const float* w; uint32_t* o;
    switch (blockIdx.y) {
        case 0: w = w0; o = o0; break;
        case 1: w = w1; o = o1; break;
        case 2: w = w2; o = o2; break;
        case 3: w = w3; o = o3; break;
        default: w = w4; o = o4; break;
    }
    int idx = blockIdx.x * 256 + threadIdx.x;    // 24576 total
    int j = idx >> 5, q = idx & 31;
    const float4 fa = *(const float4*)(w + j * HD + 8 * q);
    const float4 fb = *(const float4*)(w + j * HD + 8 * q + 4);
    uint4 r;
    r.x = pkh(fa.x, fa.y);
    r.y = pkh(fa.z, fa.w);
    r.z = pkh(fb.x, fb.y);
    r.w = pkh(fb.z, fb.w);
    ((uint4*)o)[q * G3 + j] = r;
}

// fp32 transposes for decoder-input / adj / fc1 paths
__global__ __launch_bounds__(256) void prep_small(
    const float* __restrict__ wihd,   // (768,56)
    const float* __restrict__ wadj,   // (256,512)
    const float* __restrict__ wfc1,   // (56,256)
    float* __restrict__ wihdT,        // [v][j] 56x768
    float* __restrict__ wadjT,        // [f][i] 512x256
    float* __restrict__ wfc1T)        // [k][v] 256x56
{
    int idx = blockIdx.x * 256 + threadIdx.x;    // 188416 total
    if (idx < 43008) {
        int v = idx / G3, j = idx % G3;
        wihdT[idx] = wihd[j * 56 + v];
    } else if (idx < 43008 + 131072) {
        int i2 = idx - 43008;
        int f = i2 / HD, i = i2 % HD;
        wadjT[i2] = wadj[i * 512 + f];
    } else {
        int i3 = idx - 174080;
        int k = i3 / 56, v = i3 % 56;
        wfc1T[i3] = wfc1[v * HD + k];
    }
}

// gather seq rows: seqg[(n*64+s)*192 + f] = x[n, f>>2, 8s, (f>>1)&1, f&1]
__global__ __launch_bounds__(256) void gather_seq(
    const float* __restrict__ x, float* __restrict__ seqg)
{
    int idx = blockIdx.x * 256 + threadIdx.x;    // 786432 total
    int f = idx % 192;
    int m = idx / 192;
    int n = m >> 6, s = m & 63;
    seqg[idx] = x[n * 98304 + (f >> 2) * 2048 + s * 32 + (f & 3)];
}

// ---------------- fp32 tiled GEMM with bias ----------------
__global__ __launch_bounds__(256) void gemm_bias(
    const float* __restrict__ A,
    const float* __restrict__ B0, const float* __restrict__ B1,
    const float* __restrict__ bias0, const float* __restrict__ bias1,
    float* __restrict__ C0, float* __restrict__ C1, int K)
{
    const float* B    = blockIdx.z ? B1 : B0;
    const float* bias = blockIdx.z ? bias1 : bias0;
    float*       C    = blockIdx.z ? C1 : C0;
    const int m0 = blockIdx.x * 64;
    const int n0 = blockIdx.y * 64;
    const int tid = threadIdx.x;
    const int tx = tid & 15, ty = tid >> 4;

    __shared__ float As[16][64];
    __shared__ float Bs[16][64];

    const int lm = tid >> 2;
    const int lk = (tid & 3) * 4;
    const int sw = lk << 2;

    float acc[4][4] = {};
    for (int k0 = 0; k0 < K; k0 += 16) {
        float4 a = *(const float4*)(A + (size_t)(m0 + lm) * K + k0 + lk);
        float4 b = *(const float4*)(B + (size_t)(n0 + lm) * K + k0 + lk);
        __syncthreads();
        As[lk + 0][lm ^ sw] = a.x; As[lk + 1][lm ^ sw] = a.y;
        As[lk + 2][lm ^ sw] = a.z; As[lk + 3][lm ^ sw] = a.w;
        Bs[lk + 0][lm ^ sw] = b.x; Bs[lk + 1][lm ^ sw] = b.y;
        Bs[lk + 2][lm ^ sw] = b.z; Bs[lk + 3][lm ^ sw] = b.w;
        __syncthreads();
#pragma unroll
        for (int kk = 0; kk < 16; ++kk) {
            const int swk = ((kk >> 2) & 3) << 4;
            const float4 a4 = *(const float4*)&As[kk][(ty * 4) ^ swk];
            const float4 b4 = *(const float4*)&Bs[kk][(tx * 4) ^ swk];
            const float av[4] = {a4.x, a4.y, a4.z, a4.w};
            const float bv[4] = {b4.x, b4.y, b4.z, b4.w};
#pragma unroll
            for (int i = 0; i < 4; ++i)
#pragma unroll
                for (int j = 0; j < 4; ++j)
                    acc[i][j] += av[i] * bv[j];
        }
    }
#pragma unroll
    for (int i = 0; i < 4; ++i) {
#pragma unroll
        for (int j = 0; j < 4; ++j) {
            C[(size_t)(m0 + ty * 4 + i) * G3 + n0 + tx * 4 + j] =
                acc[i][j] + bias[n0 + tx * 4 + j];
        }
    }
}

// ---------------- hybrid resident/streamed GRU scan (split-K, 512 thr) -----
// grid = 128 blocks: dir = blockIdx.x&1, n = blockIdx.x>>1.
// Thread (kh=t>>8, tr=t&255): gate rows {tr,256+tr,512+tr}, k-half kh.
// Chunks 0..5 of each gate row resident (72 dwords); chunks 6..15 streamed
// from L2 every step. Idle kh==1 half prefetches gi into LDS (double buffer).
__global__ __launch_bounds__(512, 2) void gru_scan(
    const float* __restrict__ giF, const float* __restrict__ giB,
    const uint32_t* __restrict__ wTF, const uint32_t* __restrict__ wTB,
    const float* __restrict__ bhhF, const float* __restrict__ bhhB,
    float* __restrict__ y1, float* __restrict__ hfin, int mode)
{
    const int dir = blockIdx.x & 1;
    const int n   = blockIdx.x >> 1;
    const int t   = threadIdx.x;
    const int tr  = t & 255;
    const int kh  = t >> 8;
    const int hoff = kh * 64;        // u32 offset into h buffer
    const float* gi  = dir ? giB : giF;
    const float* bhh = dir ? bhhB : bhhF;
    const uint4* wbase = (const uint4*)(dir ? wTB : wTF) + (size_t)(kh * 16) * G3 + tr;

    __shared__ __align__(16) uint32_t h1u[2][HD / 2];  // h as f16x2, dbuf
    __shared__ float ph_r[HD], ph_z[HD], ph_n[HD];     // upper-half partials
    __shared__ float gin[2][G3];                       // gi double buffer

    L6(LRES)
    const float bhr = bhh[tr], bhz = bhh[256 + tr], bhn = bhh[512 + tr];

    const float* gbase = gi + (size_t)n * NSTEP * G3;
    const int s0 = dir ? (NSTEP - 1) : 0;
#pragma unroll
    for (int i = t; i < G3; i += 512) gin[0][i] = gbase[s0 * G3 + i];

    float h_own = 0.0f;
    if (t < HD / 2) h1u[0][t] = 0u;
    __syncthreads();

    int s = s0;
    for (int step = 0; step < NSTEP; ++step) {
        const uint32_t* hb = h1u[step & 1];
        float ar0 = 0.f, ar1 = 0.f;
        float az0 = 0.f, az1 = 0.f;
        float an0 = 0.f, an1 = 0.f;
        L6(DRES)
#pragma unroll
        for (int i = 6; i < 16; ++i) {
            const uint4 sr = wbase[i * G3];
            const uint4 sz = wbase[i * G3 + 256];
            const uint4 sn = wbase[i * G3 + 512];
            const uint4 hp = *(const uint4*)&hb[hoff + 4 * i];
            ar0 = fdot2u(sr.x, hp.x, ar0); ar1 = fdot2u(sr.y, hp.y, ar1);
            ar0 = fdot2u(sr.z, hp.z, ar0); ar1 = fdot2u(sr.w, hp.w, ar1);
            az0 = fdot2u(sz.x, hp.x, az0); az1 = fdot2u(sz.y, hp.y, az1);
            az0 = fdot2u(sz.z, hp.z, az0); az1 = fdot2u(sz.w, hp.w, az1);
            an0 = fdot2u(sn.x, hp.x, an0); an1 = fdot2u(sn.y, hp.y, an1);
            an0 = fdot2u(sn.z, hp.z, an0); an1 = fdot2u(sn.w, hp.w, an1);
        }

        if (kh) {
            ph_r[tr] = ar0 + ar1;
            ph_z[tr] = az0 + az1;
            ph_n[tr] = an0 + an1;
        }
        __syncthreads();
        const int s_nxt = dir ? (step < NSTEP - 1 ? NSTEP - 2 - step : 0)
                              : (step < NSTEP - 1 ? step + 1 : NSTEP - 1);
        if (kh == 0) {
            const float* gcur = gin[step & 1];
            const float ghr = (ar0 + ar1) + ph_r[tr] + bhr;
            const float ghz = (az0 + az1) + ph_z[tr] + bhz;
            const float ghn = (an0 + an1) + ph_n[tr] + bhn;
            const float r  = sigmf(gcur[tr] + ghr);
            const float z  = sigmf(gcur[256 + tr] + ghz);
            const float nn = tanhf(gcur[512 + tr] + r * ghn);
            const float hnew = (1.0f - z) * nn + z * h_own;
            h_own = hnew;
            ((__half*)h1u[(step + 1) & 1])[tr] = __float2half(hnew);
            if (mode == 0)
                y1[(size_t)(n * NSTEP + s) * 512 + dir * HD + tr] = hnew;
        } else {
            float* gnxt = gin[(step + 1) & 1];
#pragma unroll
            for (int i = tr; i < G3; i += 256)
                gnxt[i] = gbase[s_nxt * G3 + i];
        }
        s = s_nxt;
        __syncthreads();
    }
    if (mode == 1 && kh == 0)
        hfin[(size_t)(dir * NSEQ + n) * HD + tr] = h_own;
}

// ---------------- dec_h = w_adj @ [hf,hb] + b_adj ----------------
__global__ __launch_bounds__(256) void adj_kernel(
    const float* __restrict__ hfin, const float* __restrict__ wadjT,
    const float* __restrict__ badj, float* __restrict__ dech)
{
    const int n = blockIdx.x, t = threadIdx.x;
    __shared__ float comb[512];
    comb[t]      = hfin[(size_t)n * HD + t];
    comb[HD + t] = hfin[(size_t)(NSEQ + n) * HD + t];
    __syncthreads();
    float acc = badj[t];
#pragma unroll 8
    for (int f = 0; f < 512; ++f) acc += wadjT[f * HD + t] * comb[f];
    dech[n * HD + t] = acc;
}

// ---------------- decoder: 16 blocks x 4 chains, weights fully streamed ----
// 256 threads; thread tr owns gate rows {tr,256+tr,512+tr}, full K.
// Each streamed uint4 is reused across the 4 chains (from registers).
__global__ __launch_bounds__(256, 4) void decoder_kernel(
    const float* __restrict__ dech, const uint32_t* __restrict__ wTd,
    const float* __restrict__ wihdT, const float* __restrict__ bihd,
    const float* __restrict__ bhhd, const float* __restrict__ wfc1T,
    const float* __restrict__ bfc1, float* __restrict__ out)
{
    const int nb = blockIdx.x;            // chains nb*4 .. nb*4+3
    const int tr = threadIdx.x;
    const uint4* wbase = (const uint4*)wTd + tr;

    __shared__ __align__(16) uint32_t h1u[2][4][HD / 2];
    __shared__ float hfp[4][HD];
    __shared__ float inp[4][56];

    const float bir = bihd[tr], biz = bihd[256 + tr], bin = bihd[512 + tr];
    const float bhr = bhhd[tr], bhz = bhhd[256 + tr], bhn = bhhd[512 + tr];

    float h0, h1, h2, h3;
    {
        h0 = dech[(size_t)(nb * 4 + 0) * HD + tr];
        h1 = dech[(size_t)(nb * 4 + 1) * HD + tr];
        h2 = dech[(size_t)(nb * 4 + 2) * HD + tr];
        h3 = dech[(size_t)(nb * 4 + 3) * HD + tr];
        ((__half*)h1u[0][0])[tr] = __float2half(h0);
        ((__half*)h1u[0][1])[tr] = __float2half(h1);
        ((__half*)h1u[0][2])[tr] = __float2half(h2);
        ((__half*)h1u[0][3])[tr] = __float2half(h3);
        hfp[0][tr] = h0; hfp[1][tr] = h1; hfp[2][tr] = h2; hfp[3][tr] = h3;
    }
    if (tr < 56) {
        inp[0][tr] = 0.f; inp[1][tr] = 0.f; inp[2][tr] = 0.f; inp[3][tr] = 0.f;
    }
    __syncthreads();

    for (int step = 0; step < 6; ++step) {
        float ar[4] = {}, az[4] = {}, an[4] = {};
#pragma unroll
        for (int i = 0; i < 32; ++i) {
            const uint4 sr = wbase[i * G3];
            const uint4 sz = wbase[i * G3 + 256];
            const uint4 sn = wbase[i * G3 + 512];
#pragma unroll
            for (int c = 0; c < 4; ++c) {
                const uint4 hp = *(const uint4*)&h1u[step & 1][c][4 * i];
                ar[c] = fdot2u(sr.x, hp.x, ar[c]); ar[c] = fdot2u(sr.y, hp.y, ar[c]);
                ar[c] = fdot2u(sr.z, hp.z, ar[c]); ar[c] = fdot2u(sr.w, hp.w, ar[c]);
                az[c] = fdot2u(sz.x, hp.x, az[c]); az[c] = fdot2u(sz.y, hp.y, az[c]);
                az[c] = fdot2u(sz.z, hp.z, az[c]); az[c] = fdot2u(sz.w, hp.w, az[c]);
                an[c] = fdot2u(sn.x, hp.x, an[c]); an[c] = fdot2u(sn.y, hp.y, an[c]);
                an[c] = fdot2u(sn.z, hp.z, an[c]); an[c] = fdot2u(sn.w, hp.w, an[c]);
            }
        }
        float air[4] = {}, aiz[4] = {}, ain[4] = {};
#pragma unroll 8
        for (int v = 0; v < 56; ++v) {
            const float wr = wihdT[v * G3 + tr];
            const float wz = wihdT[v * G3 + 256 + tr];
            const float wn = wihdT[v * G3 + 512 + tr];
#pragma unroll
            for (int c = 0; c < 4; ++c) {
                const float iv = inp[c][v];
                air[c] += wr * iv; aiz[c] += wz * iv; ain[c] += wn * iv;
            }
        }
        float hh[4] = {h0, h1, h2, h3};
#pragma unroll
        for (int c = 0; c < 4; ++c) {
            const float r  = sigmf(ar[c] + air[c] + bhr + bir);
            const float z  = sigmf(az[c] + aiz[c] + bhz + biz);
            const float nn = tanhf(ain[c] + bin + r * (an[c] + bhn));
            hh[c] = (1.0f - z) * nn + z * hh[c];
            ((__half*)h1u[(step + 1) & 1][c])[tr] = __float2half(hh[c]);
            hfp[c][tr] = hh[c];
        }
        h0 = hh[0]; h1 = hh[1]; h2 = hh[2]; h3 = hh[3];
        __syncthreads();
        // fc1: thread (c = tr>>6, v = tr&63 if <56): 256-MAC from LDS
        const int c = tr >> 6, v = tr & 63;
        if (v < 56) {
            float o = bfc1[v];
#pragma unroll 8
            for (int k = 0; k < HD; ++k) o += wfc1T[k * 56 + v] * hfp[c][k];
            out[(size_t)(nb * 4 + c) * 336 + step * 56 + v] = o;
            inp[c][v] = o;
        }
        __syncthreads();
    }
}

// ---------------------------------------------------------------------------
extern "C" void kernel_launch(void* const* d_in, const int* in_sizes, int n_in,
                              void* d_out, int out_size, void* d_ws, size_t ws_size,
                              hipStream_t stream)
{
    const float* x      = (const float*)d_in[0];
    const float* wih1f  = (const float*)d_in[1];
    const float* whh1f  = (const float*)d_in[2];
    const float* bih1f  = (const float*)d_in[3];
    const float* bhh1f  = (const float*)d_in[4];
    const float* wih1b  = (const float*)d_in[5];
    const float* whh1b  = (const float*)d_in[6];
    const float* bih1b  = (const float*)d_in[7];
    const float* bhh1b  = (const float*)d_in[8];
    const float* wih2f  = (const float*)d_in[9];
    const float* whh2f  = (const float*)d_in[10];
    const float* bih2f  = (const float*)d_in[11];
    const float* bhh2f  = (const float*)d_in[12];
    const float* wih2b  = (const float*)d_in[13];
    const float* whh2b  = (const float*)d_in[14];
    const float* bih2b  = (const float*)d_in[15];
    const float* bhh2b  = (const float*)d_in[16];
    const float* wihd   = (const float*)d_in[17];
    const float* whhd   = (const float*)d_in[18];
    const float* bihd   = (const float*)d_in[19];
    const float* bhhd   = (const float*)d_in[20];
    const float* wfc1   = (const float*)d_in[21];
    const float* bfc1   = (const float*)d_in[22];
    const float* wadj   = (const float*)d_in[23];
    const float* badj   = (const float*)d_in[24];

    float* ws = (float*)d_ws;
    float* seqg  = ws + 0;              // 786432
    float* gi1f  = ws + 786432;         // 3145728  (also gi2f, after scan1)
    float* gi1b  = ws + 3932160;        // 3145728  (also gi2b)
    float* y1    = ws + 7077888;        // 2097152
    float* hfin  = ws + 9175040;        // 32768
    float* dech  = ws + 9207808;        // 16384
    uint32_t* wt1f  = (uint32_t*)(ws + 9224192);   // 98304 each
    uint32_t* wt1b  = (uint32_t*)(ws + 9322496);
    uint32_t* wt2f  = (uint32_t*)(ws + 9420800);
    uint32_t* wt2b  = (uint32_t*)(ws + 9519104);
    uint32_t* wtd   = (uint32_t*)(ws + 9617408);
    float* wihdT = ws + 9715712;        // 43008
    float* wadjT = ws + 9758720;        // 131072
    float* wfc1T = ws + 9889792;        // 14336

    pack_whhT<<<dim3(96, 5), 256, 0, stream>>>(
        whh1f, whh1b, whh2f, whh2b, whhd, wt1f, wt1b, wt2f, wt2b, wtd);
    prep_small<<<736, 256, 0, stream>>>(wihd, wadj, wfc1, wihdT, wadjT, wfc1T);
    gather_seq<<<3072, 256, 0, stream>>>(x, seqg);

    // layer 1
    gemm_bias<<<dim3(64, 12, 2), 256, 0, stream>>>(
        seqg, wih1f, wih1b, bih1f, bih1b, gi1f, gi1b, 192);
    gru_scan<<<128, 512, 0, stream>>>(
        gi1f, gi1b, wt1f, wt1b, bhh1f, bhh1b, y1, hfin, 0);

    // layer 2 (gi buffers reused; stream order serializes)
    gemm_bias<<<dim3(64, 12, 2), 256, 0, stream>>>(
        y1, wih2f, wih2b, bih2f, bih2b, gi1f, gi1b, 512);
    gru_scan<<<128, 512, 0, stream>>>(
        gi1f, gi1b, wt2f, wt2b, bhh2f, bhh2b, y1, hfin, 1);

    // decoder head
    adj_kernel<<<64, 256, 0, stream>>>(hfin, wadjT, badj, dech);
    decoder_kernel<<<16, 256, 0, stream>>>(
        dech, wtd, wihdT, bihd, bhhd, wfc1T, bfc1, (float*)d_out);
}

// Round 7
// 402.832 us; speedup vs baseline: 2.7604x; 2.7604x over previous
//
#include <hip/hip_runtime.h>
#include <hip/hip_fp16.h>
#include <stdint.h>

// ---------------------------------------------------------------------------
// Problem geometry (all compile-time):
//   x: (64, 48, 512, 2, 2) fp32. seq[s,n,f] = x[n, f>>2, 8*s, (f>>1)&1, f&1]
//   (only batch rows n<64 of the 512 matter downstream).
//   Layer1 BiGRU: in=192, H=256, 64 steps. Layer2 BiGRU: in=512, H=256.
//   Only final hiddens of layer2 used. dec_h = w_adj @ [hf,hb] + b_adj.
//   Decoder GRU (in=56, H=256) 6 steps, out = w_fc1@h + b_fc1 -> (64,6,56).
//
// ROUNDS 2-6 LESSON (five failures): hipcc spills ANY large per-thread
// resident working set across the step loop (reg arrays, asm-pinned VGPRs,
// explicit AGPR writes, 4-chain accumulator batches) -> 6-132MB scratch
// traffic. The only shapes that never spilled keep <~80 live regs/thread.
// Decoder therefore: 768 thr / 1 gate-row per thread / weights STREAMED
// clean from L2 (32 coalesced uint4/step, unroll 8), 64 blocks for
// parallelism. Scan: hybrid 72-dword-resident + streamed remainder (r6,
// no spill observed).
// ---------------------------------------------------------------------------

#define HD 256
#define G3 768
#define NSEQ 64
#define NSTEP 64

typedef _Float16 hvec2 __attribute__((ext_vector_type(2)));

__device__ __forceinline__ float sigmf(float x) {
    return 1.0f / (1.0f + __expf(-x));
}

#if __has_builtin(__builtin_amdgcn_fdot2)
__device__ __forceinline__ float fdot2u(uint32_t w, uint32_t h, float acc) {
    return __builtin_amdgcn_fdot2(__builtin_bit_cast(hvec2, w),
                                  __builtin_bit_cast(hvec2, h), acc, false);
}
#else
__device__ __forceinline__ float fdot2u(uint32_t w, uint32_t h, float acc) {
    const __half2 wv = __builtin_bit_cast(__half2, w);
    const __half2 hv = __builtin_bit_cast(__half2, h);
    acc += __half2float(wv.x) * __half2float(hv.x);
    acc += __half2float(wv.y) * __half2float(hv.y);
    return acc;
}
#endif

__device__ __forceinline__ uint32_t pkh(float a, float b) {
    uint32_t lo = __half_as_ushort(__float2half_rn(a));
    uint32_t hi = __half_as_ushort(__float2half_rn(b));
    return lo | (hi << 16);
}

#define L6(X) X(0) X(1) X(2) X(3) X(4) X(5)

// resident chunks: 6 per gate row (of 16 per k-half) = 18 uint4 = 72 dwords
#define LRES(i) \
    const uint4 wr##i = wbase[(i) * G3]; \
    const uint4 wz##i = wbase[(i) * G3 + 256]; \
    const uint4 wn##i = wbase[(i) * G3 + 512];

#define DRES(i) { \
    const uint4 hp = *(const uint4*)&hb[hoff + 4 * (i)]; \
    ar0 = fdot2u(wr##i.x, hp.x, ar0); ar1 = fdot2u(wr##i.y, hp.y, ar1); \
    ar0 = fdot2u(wr##i.z, hp.z, ar0); ar1 = fdot2u(wr##i.w, hp.w, ar1); \
    az0 = fdot2u(wz##i.x, hp.x, az0); az1 = fdot2u(wz##i.y, hp.y, az1); \
    az0 = fdot2u(wz##i.z, hp.z, az0); az1 = fdot2u(wz##i.w, hp.w, az1); \
    an0 = fdot2u(wn##i.x, hp.x, an0); an1 = fdot2u(wn##i.y, hp.y, an1); \
    an0 = fdot2u(wn##i.z, hp.z, an0); an1 = fdot2u(wn##i.w, hp.w, an1); }

// ---------------- weight prep ----------------
// Repack Whh (768x256 fp32) -> uint4[q*768 + j], q=0..31: k=8q..8q+7 of row j.
__global__ __launch_bounds__(256) void pack_whhT(
    const float* __restrict__ w0, const float* __restrict__ w1,
    const float* __restrict__ w2, const float* __restrict__ w3,
    const float* __restrict__ w4,
    uint32_t* __restrict__ o0, uint32_t* __restrict__ o1,
    uint32_t* __restrict__ o2, uint32_t* __restrict__ o3,
    uint32_t* __restrict__ o4)
{
    const float* w; uint32_t* o;
    switch (blockIdx.y) {
        case 0: w = w0; o = o0; break;
        case 1: w = w1; o = o1; break;
        case 2: w = w2; o = o2; break;
        case 3: w = w3; o = o3; break;
        default: w = w4; o = o4; break;
    }
    int idx = blockIdx.x * 256 + threadIdx.x;    // 24576 total
    int j = idx >> 5, q = idx & 31;
    const float4 fa = *(const float4*)(w + j * HD + 8 * q);
    const float4 fb = *(const float4*)(w + j * HD + 8 * q + 4);
    uint4 r;
    r.x = pkh(fa.x, fa.y);
    r.y = pkh(fa.z, fa.w);
    r.z = pkh(fb.x, fb.y);
    r.w = pkh(fb.z, fb.w);
    ((uint4*)o)[q * G3 + j] = r;
}

// fp32 transposes for decoder-input / adj / fc1 paths
__global__ __launch_bounds__(256) void prep_small(
    const float* __restrict__ wihd,   // (768,56)
    const float* __restrict__ wadj,   // (256,512)
    const float* __restrict__ wfc1,   // (56,256)
    float* __restrict__ wihdT,        // [v][j] 56x768
    float* __restrict__ wadjT,        // [f][i] 512x256
    float* __restrict__ wfc1T)        // [k][v] 256x56
{
    int idx = blockIdx.x * 256 + threadIdx.x;    // 188416 total
    if (idx < 43008) {
        int v = idx / G3, j = idx % G3;
        wihdT[idx] = wihd[j * 56 + v];
    } else if (idx < 43008 + 131072) {
        int i2 = idx - 43008;
        int f = i2 / HD, i = i2 % HD;
        wadjT[i2] = wadj[i * 512 + f];
    } else {
        int i3 = idx - 174080;
        int k = i3 / 56, v = i3 % 56;
        wfc1T[i3] = wfc1[v * HD + k];
    }
}

// gather seq rows: seqg[(n*64+s)*192 + f] = x[n, f>>2, 8s, (f>>1)&1, f&1]
__global__ __launch_bounds__(256) void gather_seq(
    const float* __restrict__ x, float* __restrict__ seqg)
{
    int idx = blockIdx.x * 256 + threadIdx.x;    // 786432 total
    int f = idx % 192;
    int m = idx / 192;
    int n = m >> 6, s = m & 63;
    seqg[idx] = x[n * 98304 + (f >> 2) * 2048 + s * 32 + (f & 3)];
}

// ---------------- fp32 tiled GEMM with bias ----------------
__global__ __launch_bounds__(256) void gemm_bias(
    const float* __restrict__ A,
    const float* __restrict__ B0, const float* __restrict__ B1,
    const float* __restrict__ bias0, const float* __restrict__ bias1,
    float* __restrict__ C0, float* __restrict__ C1, int K)
{
    const float* B    = blockIdx.z ? B1 : B0;
    const float* bias = blockIdx.z ? bias1 : bias0;
    float*       C    = blockIdx.z ? C1 : C0;
    const int m0 = blockIdx.x * 64;
    const int n0 = blockIdx.y * 64;
    const int tid = threadIdx.x;
    const int tx = tid & 15, ty = tid >> 4;

    __shared__ float As[16][64];
    __shared__ float Bs[16][64];

    const int lm = tid >> 2;
    const int lk = (tid & 3) * 4;
    const int sw = lk << 2;

    float acc[4][4] = {};
    for (int k0 = 0; k0 < K; k0 += 16) {
        float4 a = *(const float4*)(A + (size_t)(m0 + lm) * K + k0 + lk);
        float4 b = *(const float4*)(B + (size_t)(n0 + lm) * K + k0 + lk);
        __syncthreads();
        As[lk + 0][lm ^ sw] = a.x; As[lk + 1][lm ^ sw] = a.y;
        As[lk + 2][lm ^ sw] = a.z; As[lk + 3][lm ^ sw] = a.w;
        Bs[lk + 0][lm ^ sw] = b.x; Bs[lk + 1][lm ^ sw] = b.y;
        Bs[lk + 2][lm ^ sw] = b.z; Bs[lk + 3][lm ^ sw] = b.w;
        __syncthreads();
#pragma unroll
        for (int kk = 0; kk < 16; ++kk) {
            const int swk = ((kk >> 2) & 3) << 4;
            const float4 a4 = *(const float4*)&As[kk][(ty * 4) ^ swk];
            const float4 b4 = *(const float4*)&Bs[kk][(tx * 4) ^ swk];
            const float av[4] = {a4.x, a4.y, a4.z, a4.w};
            const float bv[4] = {b4.x, b4.y, b4.z, b4.w};
#pragma unroll
            for (int i = 0; i < 4; ++i)
#pragma unroll
                for (int j = 0; j < 4; ++j)
                    acc[i][j] += av[i] * bv[j];
        }
    }
#pragma unroll
    for (int i = 0; i < 4; ++i) {
#pragma unroll
        for (int j = 0; j < 4; ++j) {
            C[(size_t)(m0 + ty * 4 + i) * G3 + n0 + tx * 4 + j] =
                acc[i][j] + bias[n0 + tx * 4 + j];
        }
    }
}

// ---------------- hybrid resident/streamed GRU scan (split-K, 512 thr) -----
// grid = 128 blocks: dir = blockIdx.x&1, n = blockIdx.x>>1.
// Thread (kh=t>>8, tr=t&255): gate rows {tr,256+tr,512+tr}, k-half kh.
// Chunks 0..5 of each gate row resident (72 dwords); chunks 6..15 streamed
// from L2 every step. Idle kh==1 half prefetches gi into LDS (double buffer).
__global__ __launch_bounds__(512, 2) void gru_scan(
    const float* __restrict__ giF, const float* __restrict__ giB,
    const uint32_t* __restrict__ wTF, const uint32_t* __restrict__ wTB,
    const float* __restrict__ bhhF, const float* __restrict__ bhhB,
    float* __restrict__ y1, float* __restrict__ hfin, int mode)
{
    const int dir = blockIdx.x & 1;
    const int n   = blockIdx.x >> 1;
    const int t   = threadIdx.x;
    const int tr  = t & 255;
    const int kh  = t >> 8;
    const int hoff = kh * 64;        // u32 offset into h buffer
    const float* gi  = dir ? giB : giF;
    const float* bhh = dir ? bhhB : bhhF;
    const uint4* wbase = (const uint4*)(dir ? wTB : wTF) + (size_t)(kh * 16) * G3 + tr;

    __shared__ __align__(16) uint32_t h1u[2][HD / 2];  // h as f16x2, dbuf
    __shared__ float ph_r[HD], ph_z[HD], ph_n[HD];     // upper-half partials
    __shared__ float gin[2][G3];                       // gi double buffer

    L6(LRES)
    const float bhr = bhh[tr], bhz = bhh[256 + tr], bhn = bhh[512 + tr];

    const float* gbase = gi + (size_t)n * NSTEP * G3;
    const int s0 = dir ? (NSTEP - 1) : 0;
#pragma unroll
    for (int i = t; i < G3; i += 512) gin[0][i] = gbase[s0 * G3 + i];

    float h_own = 0.0f;
    if (t < HD / 2) h1u[0][t] = 0u;
    __syncthreads();

    int s = s0;
    for (int step = 0; step < NSTEP; ++step) {
        const uint32_t* hb = h1u[step & 1];
        float ar0 = 0.f, ar1 = 0.f;
        float az0 = 0.f, az1 = 0.f;
        float an0 = 0.f, an1 = 0.f;
        L6(DRES)
#pragma unroll
        for (int i = 6; i < 16; ++i) {
            const uint4 sr = wbase[i * G3];
            const uint4 sz = wbase[i * G3 + 256];
            const uint4 sn = wbase[i * G3 + 512];
            const uint4 hp = *(const uint4*)&hb[hoff + 4 * i];
            ar0 = fdot2u(sr.x, hp.x, ar0); ar1 = fdot2u(sr.y, hp.y, ar1);
            ar0 = fdot2u(sr.z, hp.z, ar0); ar1 = fdot2u(sr.w, hp.w, ar1);
            az0 = fdot2u(sz.x, hp.x, az0); az1 = fdot2u(sz.y, hp.y, az1);
            az0 = fdot2u(sz.z, hp.z, az0); az1 = fdot2u(sz.w, hp.w, az1);
            an0 = fdot2u(sn.x, hp.x, an0); an1 = fdot2u(sn.y, hp.y, an1);
            an0 = fdot2u(sn.z, hp.z, an0); an1 = fdot2u(sn.w, hp.w, an1);
        }

        if (kh) {
            ph_r[tr] = ar0 + ar1;
            ph_z[tr] = az0 + az1;
            ph_n[tr] = an0 + an1;
        }
        __syncthreads();
        const int s_nxt = dir ? (step < NSTEP - 1 ? NSTEP - 2 - step : 0)
                              : (step < NSTEP - 1 ? step + 1 : NSTEP - 1);
        if (kh == 0) {
            const float* gcur = gin[step & 1];
            const float ghr = (ar0 + ar1) + ph_r[tr] + bhr;
            const float ghz = (az0 + az1) + ph_z[tr] + bhz;
            const float ghn = (an0 + an1) + ph_n[tr] + bhn;
            const float r  = sigmf(gcur[tr] + ghr);
            const float z  = sigmf(gcur[256 + tr] + ghz);
            const float nn = tanhf(gcur[512 + tr] + r * ghn);
            const float hnew = (1.0f - z) * nn + z * h_own;
            h_own = hnew;
            ((__half*)h1u[(step + 1) & 1])[tr] = __float2half(hnew);
            if (mode == 0)
                y1[(size_t)(n * NSTEP + s) * 512 + dir * HD + tr] = hnew;
        } else {
            float* gnxt = gin[(step + 1) & 1];
#pragma unroll
            for (int i = tr; i < G3; i += 256)
                gnxt[i] = gbase[s_nxt * G3 + i];
        }
        s = s_nxt;
        __syncthreads();
    }
    if (mode == 1 && kh == 0)
        hfin[(size_t)(dir * NSEQ + n) * HD + tr] = h_own;
}

// ---------------- dec_h = w_adj @ [hf,hb] + b_adj ----------------
__global__ __launch_bounds__(256) void adj_kernel(
    const float* __restrict__ hfin, const float* __restrict__ wadjT,
    const float* __restrict__ badj, float* __restrict__ dech)
{
    const int n = blockIdx.x, t = threadIdx.x;
    __shared__ float comb[512];
    comb[t]      = hfin[(size_t)n * HD + t];
    comb[HD + t] = hfin[(size_t)(NSEQ + n) * HD + t];
    __syncthreads();
    float acc = badj[t];
#pragma unroll 8
    for (int f = 0; f < 512; ++f) acc += wadjT[f * HD + t] * comb[f];
    dech[n * HD + t] = acc;
}

// ---------------- decoder: 64 blocks x 768 threads, streamed weights -------
// Thread j owns gate row j: 32 coalesced uint4 loads/step from L2 (no
// residency fight -> no spill). gh/gi via LDS; gates on threads<256;
// fc1 on 448 threads (8-way split-K).
__global__ __launch_bounds__(768, 3) void decoder_kernel(
    const float* __restrict__ dech, const uint32_t* __restrict__ wTd,
    const float* __restrict__ wihdT, const float* __restrict__ bihd,
    const float* __restrict__ bhhd, const float* __restrict__ wfc1T,
    const float* __restrict__ bfc1, float* __restrict__ out)
{
    const int n = blockIdx.x, t = threadIdx.x;
    const uint4* wq = (const uint4*)wTd + t;

    __shared__ __align__(16) uint32_t h1u[2][HD / 2];
    __shared__ float ghs[G3], gis[G3];
    __shared__ float hfp[HD];
    __shared__ float inp[56];
    __shared__ float pf1[448];

    const float bi = bihd[t], bh = bhhd[t];

    float h_own = 0.0f;
    if (t < HD) {
        const float hv = dech[(size_t)n * HD + t];
        h_own = hv;
        ((__half*)h1u[0])[t] = __float2half(hv);
        hfp[t] = hv;
    }
    if (t < 56) inp[t] = 0.0f;
    __syncthreads();

    for (int step = 0; step < 6; ++step) {
        const uint32_t* hb = h1u[step & 1];
        float a0 = 0.f, a1 = 0.f;
#pragma unroll 8
        for (int q = 0; q < 32; ++q) {
            const uint4 w = wq[q * G3];
            const uint4 hp = *(const uint4*)&hb[4 * q];
            a0 = fdot2u(w.x, hp.x, a0); a1 = fdot2u(w.y, hp.y, a1);
            a0 = fdot2u(w.z, hp.z, a0); a1 = fdot2u(w.w, hp.w, a1);
        }
        float ai = bi;
#pragma unroll 8
        for (int v = 0; v < 56; ++v) ai += wihdT[v * G3 + t] * inp[v];
        ghs[t] = a0 + a1 + bh;
        gis[t] = ai;
        __syncthreads();
        if (t < HD) {
            const float r  = sigmf(gis[t] + ghs[t]);
            const float z  = sigmf(gis[HD + t] + ghs[HD + t]);
            const float nn = tanhf(gis[2 * HD + t] + r * ghs[2 * HD + t]);
            const float hnew = (1.0f - z) * nn + z * h_own;
            h_own = hnew;
            ((__half*)h1u[(step + 1) & 1])[t] = __float2half(hnew);
            hfp[t] = hnew;
        }
        __syncthreads();
        if (t < 448) {
            const int v = t >> 3, g = t & 7;
            float o = 0.f;
#pragma unroll
            for (int k2 = 0; k2 < 32; ++k2)
                o += wfc1T[(g * 32 + k2) * 56 + v] * hfp[g * 32 + k2];
            pf1[t] = o;
        }
        __syncthreads();
        if (t < 56) {
            float o = bfc1[t];
#pragma unroll
            for (int g = 0; g < 8; ++g) o += pf1[t * 8 + g];
            out[(size_t)n * 336 + step * 56 + t] = o;
            inp[t] = o;
        }
        __syncthreads();
    }
}

// ---------------------------------------------------------------------------
extern "C" void kernel_launch(void* const* d_in, const int* in_sizes, int n_in,
                              void* d_out, int out_size, void* d_ws, size_t ws_size,
                              hipStream_t stream)
{
    const float* x      = (const float*)d_in[0];
    const float* wih1f  = (const float*)d_in[1];
    const float* whh1f  = (const float*)d_in[2];
    const float* bih1f  = (const float*)d_in[3];
    const float* bhh1f  = (const float*)d_in[4];
    const float* wih1b  = (const float*)d_in[5];
    const float* whh1b  = (const float*)d_in[6];
    const float* bih1b  = (const float*)d_in[7];
    const float* bhh1b  = (const float*)d_in[8];
    const float* wih2f  = (const float*)d_in[9];
    const float* whh2f  = (const float*)d_in[10];
    const float* bih2f  = (const float*)d_in[11];
    const float* bhh2f  = (const float*)d_in[12];
    const float* wih2b  = (const float*)d_in[13];
    const float* whh2b  = (const float*)d_in[14];
    const float* bih2b  = (const float*)d_in[15];
    const float* bhh2b  = (const float*)d_in[16];
    const float* wihd   = (const float*)d_in[17];
    const float* whhd   = (const float*)d_in[18];
    const float* bihd   = (const float*)d_in[19];
    const float* bhhd   = (const float*)d_in[20];
    const float* wfc1   = (const float*)d_in[21];
    const float* bfc1   = (const float*)d_in[22];
    const float* wadj   = (const float*)d_in[23];
    const float* badj   = (const float*)d_in[24];

    float* ws = (float*)d_ws;
    float* seqg  = ws + 0;              // 786432
    float* gi1f  = ws + 786432;         // 3145728  (also gi2f, after scan1)
    float* gi1b  = ws + 3932160;        // 3145728  (also gi2b)
    float* y1    = ws + 7077888;        // 2097152
    float* hfin  = ws + 9175040;        // 32768
    float* dech  = ws + 9207808;        // 16384
    uint32_t* wt1f  = (uint32_t*)(ws + 9224192);   // 98304 each
    uint32_t* wt1b  = (uint32_t*)(ws + 9322496);
    uint32_t* wt2f  = (uint32_t*)(ws + 9420800);
    uint32_t* wt2b  = (uint32_t*)(ws + 9519104);
    uint32_t* wtd   = (uint32_t*)(ws + 9617408);
    float* wihdT = ws + 9715712;        // 43008
    float* wadjT = ws + 9758720;        // 131072
    float* wfc1T = ws + 9889792;        // 14336

    pack_whhT<<<dim3(96, 5), 256, 0, stream>>>(
        whh1f, whh1b, whh2f, whh2b, whhd, wt1f, wt1b, wt2f, wt2b, wtd);
    prep_small<<<736, 256, 0, stream>>>(wihd, wadj, wfc1, wihdT, wadjT, wfc1T);
    gather_seq<<<3072, 256, 0, stream>>>(x, seqg);

    // layer 1
    gemm_bias<<<dim3(64, 12, 2), 256, 0, stream>>>(
        seqg, wih1f, wih1b, bih1f, bih1b, gi1f, gi1b, 192);
    gru_scan<<<128, 512, 0, stream>>>(
        gi1f, gi1b, wt1f, wt1b, bhh1f, bhh1b, y1, hfin, 0);

    // layer 2 (gi buffers reused; stream order serializes)
    gemm_bias<<<dim3(64, 12, 2), 256, 0, stream>>>(
        y1, wih2f, wih2b, bih2f, bih2b, gi1f, gi1b, 512);
    gru_scan<<<128, 512, 0, stream>>>(
        gi1f, gi1b, wt2f, wt2b, bhh2f, bhh2b, y1, hfin, 1);

    // decoder head
    adj_kernel<<<64, 256, 0, stream>>>(hfin, wadjT, badj, dech);
    decoder_kernel<<<64, 768, 0, stream>>>(
        dech, wtd, wihdT, bihd, bhhd, wfc1T, bfc1, (float*)d_out);
}

// Round 8
// 391.067 us; speedup vs baseline: 2.8434x; 1.0301x over previous
//
#include <hip/hip_runtime.h>
#include <hip/hip_fp16.h>
#include <stdint.h>

// ---------------------------------------------------------------------------
// Problem geometry (all compile-time):
//   x: (64, 48, 512, 2, 2) fp32. seq[s,n,f] = x[n, f>>2, 8*s, (f>>1)&1, f&1]
//   (only batch rows n<64 of the 512 matter downstream).
//   Layer1 BiGRU: in=192, H=256, 64 steps. Layer2 BiGRU: in=512, H=256.
//   Only final hiddens of layer2 used. dec_h = w_adj @ [hf,hb] + b_adj.
//   Decoder GRU (in=56, H=256) 6 steps, out = w_fc1@h + b_fc1 -> (64,6,56).
//
// REGISTER-RESIDENCY LEDGER (r2-r7):
//   - (768 thr) cap 170 -> spill.  - (512,2) cap 128 -> spill (r4).
//   - (256,1) allocator DID allocate 256 VGPRs (r3) -> 256 is reachable
//     when launch_bounds allows and demand <= 256.
//   - AGPR asm parking: spilled around volatile asm (r5). Dead end.
//   - Streamed-from-L2 loop: works, no spill, but latency-bound at 25%
//     VALUBusy, 1.5us/step (r7).
// => Scan v8: __launch_bounds__(512,1) (cap 256), 48 resident uint4 = 192
//    dwords + ~35 working ~= 230 < 256. Zero loads in the step loop.
// Decoder: r7 shape (768 thr, streamed, 64 blocks) - works, ~20us.
// ---------------------------------------------------------------------------

#define HD 256
#define G3 768
#define NSEQ 64
#define NSTEP 64

typedef _Float16 hvec2 __attribute__((ext_vector_type(2)));

__device__ __forceinline__ float sigmf(float x) {
    return 1.0f / (1.0f + __expf(-x));
}

#if __has_builtin(__builtin_amdgcn_fdot2)
__device__ __forceinline__ float fdot2u(uint32_t w, uint32_t h, float acc) {
    return __builtin_amdgcn_fdot2(__builtin_bit_cast(hvec2, w),
                                  __builtin_bit_cast(hvec2, h), acc, false);
}
#else
__device__ __forceinline__ float fdot2u(uint32_t w, uint32_t h, float acc) {
    const __half2 wv = __builtin_bit_cast(__half2, w);
    const __half2 hv = __builtin_bit_cast(__half2, h);
    acc += __half2float(wv.x) * __half2float(hv.x);
    acc += __half2float(wv.y) * __half2float(hv.y);
    return acc;
}
#endif

__device__ __forceinline__ uint32_t pkh(float a, float b) {
    uint32_t lo = __half_as_ushort(__float2half_rn(a));
    uint32_t hi = __half_as_ushort(__float2half_rn(b));
    return lo | (hi << 16);
}

#define L16(X) X(0) X(1) X(2) X(3) X(4) X(5) X(6) X(7) \
  X(8) X(9) X(10) X(11) X(12) X(13) X(14) X(15)

// fully-resident: 16 chunks per gate row x 3 rows = 48 uint4 = 192 dwords
#define LRES(i) \
    const uint4 wr##i = wbase[(i) * G3]; \
    const uint4 wz##i = wbase[(i) * G3 + 256]; \
    const uint4 wn##i = wbase[(i) * G3 + 512];

#define DRES(i) { \
    const uint4 hp = *(const uint4*)&hb[hoff + 4 * (i)]; \
    ar0 = fdot2u(wr##i.x, hp.x, ar0); ar1 = fdot2u(wr##i.y, hp.y, ar1); \
    ar0 = fdot2u(wr##i.z, hp.z, ar0); ar1 = fdot2u(wr##i.w, hp.w, ar1); \
    az0 = fdot2u(wz##i.x, hp.x, az0); az1 = fdot2u(wz##i.y, hp.y, az1); \
    az0 = fdot2u(wz##i.z, hp.z, az0); az1 = fdot2u(wz##i.w, hp.w, az1); \
    an0 = fdot2u(wn##i.x, hp.x, an0); an1 = fdot2u(wn##i.y, hp.y, an1); \
    an0 = fdot2u(wn##i.z, hp.z, an0); an1 = fdot2u(wn##i.w, hp.w, an1); }

// ---------------- weight prep ----------------
// Repack Whh (768x256 fp32) -> uint4[q*768 + j], q=0..31: k=8q..8q+7 of row j.
__global__ __launch_bounds__(256) void pack_whhT(
    const float* __restrict__ w0, const float* __restrict__ w1,
    const float* __restrict__ w2, const float* __restrict__ w3,
    const float* __restrict__ w4,
    uint32_t* __restrict__ o0, uint32_t* __restrict__ o1,
    uint32_t* __restrict__ o2, uint32_t* __restrict__ o3,
    uint32_t* __restrict__ o4)
{
    const float* w; uint32_t* o;
    switch (blockIdx.y) {
        case 0: w = w0; o = o0; break;
        case 1: w = w1; o = o1; break;
        case 2: w = w2; o = o2; break;
        case 3: w = w3; o = o3; break;
        default: w = w4; o = o4; break;
    }
    int idx = blockIdx.x * 256 + threadIdx.x;    // 24576 total
    int j = idx >> 5, q = idx & 31;
    const float4 fa = *(const float4*)(w + j * HD + 8 * q);
    const float4 fb = *(const float4*)(w + j * HD + 8 * q + 4);
    uint4 r;
    r.x = pkh(fa.x, fa.y);
    r.y = pkh(fa.z, fa.w);
    r.z = pkh(fb.x, fb.y);
    r.w = pkh(fb.z, fb.w);
    ((uint4*)o)[q * G3 + j] = r;
}

// fp32 transposes for decoder-input / adj / fc1 paths
__global__ __launch_bounds__(256) void prep_small(
    const float* __restrict__ wihd,   // (768,56)
    const float* __restrict__ wadj,   // (256,512)
    const float* __restrict__ wfc1,   // (56,256)
    float* __restrict__ wihdT,        // [v][j] 56x768
    float* __restrict__ wadjT,        // [f][i] 512x256
    float* __restrict__ wfc1T)        // [k][v] 256x56
{
    int idx = blockIdx.x * 256 + threadIdx.x;    // 188416 total
    if (idx < 43008) {
        int v = idx / G3, j = idx % G3;
        wihdT[idx] = wihd[j * 56 + v];
    } else if (idx < 43008 + 131072) {
        int i2 = idx - 43008;
        int f = i2 / HD, i = i2 % HD;
        wadjT[i2] = wadj[i * 512 + f];
    } else {
        int i3 = idx - 174080;
        int k = i3 / 56, v = i3 % 56;
        wfc1T[i3] = wfc1[v * HD + k];
    }
}

// gather seq rows: seqg[(n*64+s)*192 + f] = x[n, f>>2, 8s, (f>>1)&1, f&1]
__global__ __launch_bounds__(256) void gather_seq(
    const float* __restrict__ x, float* __restrict__ seqg)
{
    int idx = blockIdx.x * 256 + threadIdx.x;    // 786432 total
    int f = idx % 192;
    int m = idx / 192;
    int n = m >> 6, s = m & 63;
    seqg[idx] = x[n * 98304 + (f >> 2) * 2048 + s * 32 + (f & 3)];
}

// ---------------- fp32 tiled GEMM with bias ----------------
__global__ __launch_bounds__(256) void gemm_bias(
    const float* __restrict__ A,
    const float* __restrict__ B0, const float* __restrict__ B1,
    const float* __restrict__ bias0, const float* __restrict__ bias1,
    float* __restrict__ C0, float* __restrict__ C1, int K)
{
    const float* B    = blockIdx.z ? B1 : B0;
    const float* bias = blockIdx.z ? bias1 : bias0;
    float*       C    = blockIdx.z ? C1 : C0;
    const int m0 = blockIdx.x * 64;
    const int n0 = blockIdx.y * 64;
    const int tid = threadIdx.x;
    const int tx = tid & 15, ty = tid >> 4;

    __shared__ float As[16][64];
    __shared__ float Bs[16][64];

    const int lm = tid >> 2;
    const int lk = (tid & 3) * 4;
    const int sw = lk << 2;

    float acc[4][4] = {};
    for (int k0 = 0; k0 < K; k0 += 16) {
        float4 a = *(const float4*)(A + (size_t)(m0 + lm) * K + k0 + lk);
        float4 b = *(const float4*)(B + (size_t)(n0 + lm) * K + k0 + lk);
        __syncthreads();
        As[lk + 0][lm ^ sw] = a.x; As[lk + 1][lm ^ sw] = a.y;
        As[lk + 2][lm ^ sw] = a.z; As[lk + 3][lm ^ sw] = a.w;
        Bs[lk + 0][lm ^ sw] = b.x; Bs[lk + 1][lm ^ sw] = b.y;
        Bs[lk + 2][lm ^ sw] = b.z; Bs[lk + 3][lm ^ sw] = b.w;
        __syncthreads();
#pragma unroll
        for (int kk = 0; kk < 16; ++kk) {
            const int swk = ((kk >> 2) & 3) << 4;
            const float4 a4 = *(const float4*)&As[kk][(ty * 4) ^ swk];
            const float4 b4 = *(const float4*)&Bs[kk][(tx * 4) ^ swk];
            const float av[4] = {a4.x, a4.y, a4.z, a4.w};
            const float bv[4] = {b4.x, b4.y, b4.z, b4.w};
#pragma unroll
            for (int i = 0; i < 4; ++i)
#pragma unroll
                for (int j = 0; j < 4; ++j)
                    acc[i][j] += av[i] * bv[j];
        }
    }
#pragma unroll
    for (int i = 0; i < 4; ++i) {
#pragma unroll
        for (int j = 0; j < 4; ++j) {
            C[(size_t)(m0 + ty * 4 + i) * G3 + n0 + tx * 4 + j] =
                acc[i][j] + bias[n0 + tx * 4 + j];
        }
    }
}

// ---------------- fully-resident GRU scan (split-K, 512 thr, 256 VGPR) -----
// grid = 128 blocks: dir = blockIdx.x&1, n = blockIdx.x>>1.
// Thread (kh=t>>8, tr=t&255): gate rows {tr,256+tr,512+tr}, k-half kh.
// All 48 uint4 weight chunks register-resident; NO loads in the step loop.
// kh==1 half prefetches next step's gi into LDS during the gate phase.
__global__ __launch_bounds__(512, 1) void gru_scan(
    const float* __restrict__ giF, const float* __restrict__ giB,
    const uint32_t* __restrict__ wTF, const uint32_t* __restrict__ wTB,
    const float* __restrict__ bhhF, const float* __restrict__ bhhB,
    float* __restrict__ y1, float* __restrict__ hfin, int mode)
{
    const int dir = blockIdx.x & 1;
    const int n   = blockIdx.x >> 1;
    const int t   = threadIdx.x;
    const int tr  = t & 255;
    const int kh  = t >> 8;
    const int hoff = kh * 64;        // u32 offset into h buffer
    const float* gi  = dir ? giB : giF;
    const float* bhh = dir ? bhhB : bhhF;
    const uint4* wbase = (const uint4*)(dir ? wTB : wTF) + (size_t)(kh * 16) * G3 + tr;

    __shared__ __align__(16) uint32_t h1u[2][HD / 2];  // h as f16x2, dbuf
    __shared__ float ph_r[HD], ph_z[HD], ph_n[HD];     // upper-half partials
    __shared__ float gin[2][G3];                       // gi double buffer

    L16(LRES)
    const float bhr = bhh[tr], bhz = bhh[256 + tr], bhn = bhh[512 + tr];

    const float* gbase = gi + (size_t)n * NSTEP * G3;
    const int s0 = dir ? (NSTEP - 1) : 0;
#pragma unroll
    for (int i = t; i < G3; i += 512) gin[0][i] = gbase[s0 * G3 + i];

    float h_own = 0.0f;
    if (t < HD / 2) h1u[0][t] = 0u;
    __syncthreads();

    int s = s0;
    for (int step = 0; step < NSTEP; ++step) {
        const uint32_t* hb = h1u[step & 1];
        float ar0 = 0.f, ar1 = 0.f;
        float az0 = 0.f, az1 = 0.f;
        float an0 = 0.f, an1 = 0.f;
        L16(DRES)

        if (kh) {
            ph_r[tr] = ar0 + ar1;
            ph_z[tr] = az0 + az1;
            ph_n[tr] = an0 + an1;
        }
        __syncthreads();
        const int s_nxt = dir ? (step < NSTEP - 1 ? NSTEP - 2 - step : 0)
                              : (step < NSTEP - 1 ? step + 1 : NSTEP - 1);
        if (kh == 0) {
            const float* gcur = gin[step & 1];
            const float ghr = (ar0 + ar1) + ph_r[tr] + bhr;
            const float ghz = (az0 + az1) + ph_z[tr] + bhz;
            const float ghn = (an0 + an1) + ph_n[tr] + bhn;
            const float r  = sigmf(gcur[tr] + ghr);
            const float z  = sigmf(gcur[256 + tr] + ghz);
            const float nn = tanhf(gcur[512 + tr] + r * ghn);
            const float hnew = (1.0f - z) * nn + z * h_own;
            h_own = hnew;
            ((__half*)h1u[(step + 1) & 1])[tr] = __float2half(hnew);
            if (mode == 0)
                y1[(size_t)(n * NSTEP + s) * 512 + dir * HD + tr] = hnew;
        } else {
            float* gnxt = gin[(step + 1) & 1];
#pragma unroll
            for (int i = tr; i < G3; i += 256)
                gnxt[i] = gbase[s_nxt * G3 + i];
        }
        s = s_nxt;
        __syncthreads();
    }
    if (mode == 1 && kh == 0)
        hfin[(size_t)(dir * NSEQ + n) * HD + tr] = h_own;
}

// ---------------- dec_h = w_adj @ [hf,hb] + b_adj ----------------
__global__ __launch_bounds__(256) void adj_kernel(
    const float* __restrict__ hfin, const float* __restrict__ wadjT,
    const float* __restrict__ badj, float* __restrict__ dech)
{
    const int n = blockIdx.x, t = threadIdx.x;
    __shared__ float comb[512];
    comb[t]      = hfin[(size_t)n * HD + t];
    comb[HD + t] = hfin[(size_t)(NSEQ + n) * HD + t];
    __syncthreads();
    float acc = badj[t];
#pragma unroll 8
    for (int f = 0; f < 512; ++f) acc += wadjT[f * HD + t] * comb[f];
    dech[n * HD + t] = acc;
}

// ---------------- decoder: 64 blocks x 768 threads, streamed weights -------
// Thread j owns gate row j: 32 coalesced uint4 loads/step from L2 (no
// residency fight -> no spill). gh/gi via LDS; gates on threads<256;
// fc1 on 448 threads (8-way split-K).
__global__ __launch_bounds__(768, 3) void decoder_kernel(
    const float* __restrict__ dech, const uint32_t* __restrict__ wTd,
    const float* __restrict__ wihdT, const float* __restrict__ bihd,
    const float* __restrict__ bhhd, const float* __restrict__ wfc1T,
    const float* __restrict__ bfc1, float* __restrict__ out)
{
    const int n = blockIdx.x, t = threadIdx.x;
    const uint4* wq = (const uint4*)wTd + t;

    __shared__ __align__(16) uint32_t h1u[2][HD / 2];
    __shared__ float ghs[G3], gis[G3];
    __shared__ float hfp[HD];
    __shared__ float inp[56];
    __shared__ float pf1[448];

    const float bi = bihd[t], bh = bhhd[t];

    float h_own = 0.0f;
    if (t < HD) {
        const float hv = dech[(size_t)n * HD + t];
        h_own = hv;
        ((__half*)h1u[0])[t] = __float2half(hv);
        hfp[t] = hv;
    }
    if (t < 56) inp[t] = 0.0f;
    __syncthreads();

    for (int step = 0; step < 6; ++step) {
        const uint32_t* hb = h1u[step & 1];
        float a0 = 0.f, a1 = 0.f;
#pragma unroll 8
        for (int q = 0; q < 32; ++q) {
            const uint4 w = wq[q * G3];
            const uint4 hp = *(const uint4*)&hb[4 * q];
            a0 = fdot2u(w.x, hp.x, a0); a1 = fdot2u(w.y, hp.y, a1);
            a0 = fdot2u(w.z, hp.z, a0); a1 = fdot2u(w.w, hp.w, a1);
        }
        float ai = bi;
#pragma unroll 8
        for (int v = 0; v < 56; ++v) ai += wihdT[v * G3 + t] * inp[v];
        ghs[t] = a0 + a1 + bh;
        gis[t] = ai;
        __syncthreads();
        if (t < HD) {
            const float r  = sigmf(gis[t] + ghs[t]);
            const float z  = sigmf(gis[HD + t] + ghs[HD + t]);
            const float nn = tanhf(gis[2 * HD + t] + r * ghs[2 * HD + t]);
            const float hnew = (1.0f - z) * nn + z * h_own;
            h_own = hnew;
            ((__half*)h1u[(step + 1) & 1])[t] = __float2half(hnew);
            hfp[t] = hnew;
        }
        __syncthreads();
        if (t < 448) {
            const int v = t >> 3, g = t & 7;
            float o = 0.f;
#pragma unroll
            for (int k2 = 0; k2 < 32; ++k2)
                o += wfc1T[(g * 32 + k2) * 56 + v] * hfp[g * 32 + k2];
            pf1[t] = o;
        }
        __syncthreads();
        if (t < 56) {
            float o = bfc1[t];
#pragma unroll
            for (int g = 0; g < 8; ++g) o += pf1[t * 8 + g];
            out[(size_t)n * 336 + step * 56 + t] = o;
            inp[t] = o;
        }
        __syncthreads();
    }
}

// ---------------------------------------------------------------------------
extern "C" void kernel_launch(void* const* d_in, const int* in_sizes, int n_in,
                              void* d_out, int out_size, void* d_ws, size_t ws_size,
                              hipStream_t stream)
{
    const float* x      = (const float*)d_in[0];
    const float* wih1f  = (const float*)d_in[1];
    const float* whh1f  = (const float*)d_in[2];
    const float* bih1f  = (const float*)d_in[3];
    const float* bhh1f  = (const float*)d_in[4];
    const float* wih1b  = (const float*)d_in[5];
    const float* whh1b  = (const float*)d_in[6];
    const float* bih1b  = (const float*)d_in[7];
    const float* bhh1b  = (const float*)d_in[8];
    const float* wih2f  = (const float*)d_in[9];
    const float* whh2f  = (const float*)d_in[10];
    const float* bih2f  = (const float*)d_in[11];
    const float* bhh2f  = (const float*)d_in[12];
    const float* wih2b  = (const float*)d_in[13];
    const float* whh2b  = (const float*)d_in[14];
    const float* bih2b  = (const float*)d_in[15];
    const float* bhh2b  = (const float*)d_in[16];
    const float* wihd   = (const float*)d_in[17];
    const float* whhd   = (const float*)d_in[18];
    const float* bihd   = (const float*)d_in[19];
    const float* bhhd   = (const float*)d_in[20];
    const float* wfc1   = (const float*)d_in[21];
    const float* bfc1   = (const float*)d_in[22];
    const float* wadj   = (const float*)d_in[23];
    const float* badj   = (const float*)d_in[24];

    float* ws = (float*)d_ws;
    float* seqg  = ws + 0;              // 786432
    float* gi1f  = ws + 786432;         // 3145728  (also gi2f, after scan1)
    float* gi1b  = ws + 3932160;        // 3145728  (also gi2b)
    float* y1    = ws + 7077888;        // 2097152
    float* hfin  = ws + 9175040;        // 32768
    float* dech  = ws + 9207808;        // 16384
    uint32_t* wt1f  = (uint32_t*)(ws + 9224192);   // 98304 each
    uint32_t* wt1b  = (uint32_t*)(ws + 9322496);
    uint32_t* wt2f  = (uint32_t*)(ws + 9420800);
    uint32_t* wt2b  = (uint32_t*)(ws + 9519104);
    uint32_t* wtd   = (uint32_t*)(ws + 9617408);
    float* wihdT = ws + 9715712;        // 43008
    float* wadjT = ws + 9758720;        // 131072
    float* wfc1T = ws + 9889792;        // 14336

    pack_whhT<<<dim3(96, 5), 256, 0, stream>>>(
        whh1f, whh1b, whh2f, whh2b, whhd, wt1f, wt1b, wt2f, wt2b, wtd);
    prep_small<<<736, 256, 0, stream>>>(wihd, wadj, wfc1, wihdT, wadjT, wfc1T);
    gather_seq<<<3072, 256, 0, stream>>>(x, seqg);

    // layer 1
    gemm_bias<<<dim3(64, 12, 2), 256, 0, stream>>>(
        seqg, wih1f, wih1b, bih1f, bih1b, gi1f, gi1b, 192);
    gru_scan<<<128, 512, 0, stream>>>(
        gi1f, gi1b, wt1f, wt1b, bhh1f, bhh1b, y1, hfin, 0);

    // layer 2 (gi buffers reused; stream order serializes)
    gemm_bias<<<dim3(64, 12, 2), 256, 0, stream>>>(
        y1, wih2f, wih2b, bih2f, bih2b, gi1f, gi1b, 512);
    gru_scan<<<128, 512, 0, stream>>>(
        gi1f, gi1b, wt2f, wt2b, bhh2f, bhh2b, y1, hfin, 1);

    // decoder head
    adj_kernel<<<64, 256, 0, stream>>>(hfin, wadjT, badj, dech);
    decoder_kernel<<<64, 768, 0, stream>>>(
        dech, wtd, wihdT, bihd, bhhd, wfc1T, bfc1, (float*)d_out);
}

// Round 9
// 353.203 us; speedup vs baseline: 3.1482x; 1.1072x over previous
//
#include <hip/hip_runtime.h>
#include <hip/hip_fp16.h>
#include <stdint.h>

// ---------------------------------------------------------------------------
// Problem geometry (all compile-time):
//   x: (64, 48, 512, 2, 2) fp32. seq[s,n,f] = x[n, f>>2, 8*s, (f>>1)&1, f&1]
//   (only batch rows n<64 of the 512 matter downstream).
//   Layer1 BiGRU: in=192, H=256, 64 steps. Layer2 BiGRU: in=512, H=256.
//   Only final hiddens of layer2 used. dec_h = w_adj @ [hf,hb] + b_adj.
//   Decoder GRU (in=56, H=256) 6 steps, out = w_fc1@h + b_fc1 -> (64,6,56).
//
// r8 counters: gemm_bias (fp32 VALU, 95us x2, 3.1M bank conflicts) is the
// bottleneck -> replaced with MFMA f16 GEMM (no LDS, L2-resident operands,
// fp32 accumulate). A-side inputs (seq, y1) now stored f16 by producers;
// y1 was already f16-rounded for the scan's own h-buffer, so no extra loss.
// REGISTER-RESIDENCY LEDGER (r2-r7) for the scans: see gru_scan comment.
// ---------------------------------------------------------------------------

#define HD 256
#define G3 768
#define NSEQ 64
#define NSTEP 64

typedef _Float16 hvec2 __attribute__((ext_vector_type(2)));
typedef _Float16 f16x8 __attribute__((ext_vector_type(8)));
typedef float f32x4 __attribute__((ext_vector_type(4)));

__device__ __forceinline__ float sigmf(float x) {
    return 1.0f / (1.0f + __expf(-x));
}

#if __has_builtin(__builtin_amdgcn_fdot2)
__device__ __forceinline__ float fdot2u(uint32_t w, uint32_t h, float acc) {
    return __builtin_amdgcn_fdot2(__builtin_bit_cast(hvec2, w),
                                  __builtin_bit_cast(hvec2, h), acc, false);
}
#else
__device__ __forceinline__ float fdot2u(uint32_t w, uint32_t h, float acc) {
    const __half2 wv = __builtin_bit_cast(__half2, w);
    const __half2 hv = __builtin_bit_cast(__half2, h);
    acc += __half2float(wv.x) * __half2float(hv.x);
    acc += __half2float(wv.y) * __half2float(hv.y);
    return acc;
}
#endif

__device__ __forceinline__ uint32_t pkh(float a, float b) {
    uint32_t lo = __half_as_ushort(__float2half_rn(a));
    uint32_t hi = __half_as_ushort(__float2half_rn(b));
    return lo | (hi << 16);
}

#define L16(X) X(0) X(1) X(2) X(3) X(4) X(5) X(6) X(7) \
  X(8) X(9) X(10) X(11) X(12) X(13) X(14) X(15)

// fully-resident: 16 chunks per gate row x 3 rows = 48 uint4 = 192 dwords
#define LRES(i) \
    const uint4 wr##i = wbase[(i) * G3]; \
    const uint4 wz##i = wbase[(i) * G3 + 256]; \
    const uint4 wn##i = wbase[(i) * G3 + 512];

#define DRES(i) { \
    const uint4 hp = *(const uint4*)&hb[hoff + 4 * (i)]; \
    ar0 = fdot2u(wr##i.x, hp.x, ar0); ar1 = fdot2u(wr##i.y, hp.y, ar1); \
    ar0 = fdot2u(wr##i.z, hp.z, ar0); ar1 = fdot2u(wr##i.w, hp.w, ar1); \
    az0 = fdot2u(wz##i.x, hp.x, az0); az1 = fdot2u(wz##i.y, hp.y, az1); \
    az0 = fdot2u(wz##i.z, hp.z, az0); az1 = fdot2u(wz##i.w, hp.w, az1); \
    an0 = fdot2u(wn##i.x, hp.x, an0); an1 = fdot2u(wn##i.y, hp.y, an1); \
    an0 = fdot2u(wn##i.z, hp.z, an0); an1 = fdot2u(wn##i.w, hp.w, an1); }

// ---------------- weight prep ----------------
// Repack Whh (768x256 fp32) -> uint4[q*768 + j], q=0..31: k=8q..8q+7 of row j.
__global__ __launch_bounds__(256) void pack_whhT(
    const float* __restrict__ w0, const float* __restrict__ w1,
    const float* __restrict__ w2, const float* __restrict__ w3,
    const float* __restrict__ w4,
    uint32_t* __restrict__ o0, uint32_t* __restrict__ o1,
    uint32_t* __restrict__ o2, uint32_t* __restrict__ o3,
    uint32_t* __restrict__ o4)
{
    const float* w; uint32_t* o;
    switch (blockIdx.y) {
        case 0: w = w0; o = o0; break;
        case 1: w = w1; o = o1; break;
        case 2: w = w2; o = o2; break;
        case 3: w = w3; o = o3; break;
        default: w = w4; o = o4; break;
    }
    int idx = blockIdx.x * 256 + threadIdx.x;    // 24576 total
    int j = idx >> 5, q = idx & 31;
    const float4 fa = *(const float4*)(w + j * HD + 8 * q);
    const float4 fb = *(const float4*)(w + j * HD + 8 * q + 4);
    uint4 r;
    r.x = pkh(fa.x, fa.y);
    r.y = pkh(fa.z, fa.w);
    r.z = pkh(fb.x, fb.y);
    r.w = pkh(fb.z, fb.w);
    ((uint4*)o)[q * G3 + j] = r;
}

// Wih fp32 -> f16 (same row-major layout), 4 tensors
__global__ __launch_bounds__(256) void pack_wih(
    const float* __restrict__ s0, const float* __restrict__ s1,
    const float* __restrict__ s2, const float* __restrict__ s3,
    __half* __restrict__ d0, __half* __restrict__ d1,
    __half* __restrict__ d2, __half* __restrict__ d3)
{
    const float* s; __half* d; int sz;
    switch (blockIdx.y) {
        case 0: s = s0; d = d0; sz = 147456; break;
        case 1: s = s1; d = d1; sz = 147456; break;
        case 2: s = s2; d = d2; sz = 393216; break;
        default: s = s3; d = d3; sz = 393216; break;
    }
    int i4 = blockIdx.x * 256 + threadIdx.x;
    if (i4 * 4 >= sz) return;
    const float4 v = *(const float4*)(s + i4 * 4);
    __half2 lo; lo.x = __float2half_rn(v.x); lo.y = __float2half_rn(v.y);
    __half2 hi; hi.x = __float2half_rn(v.z); hi.y = __float2half_rn(v.w);
    *(__half2*)(d + i4 * 4)     = lo;
    *(__half2*)(d + i4 * 4 + 2) = hi;
}

// fp32 transposes for decoder-input / adj / fc1 paths
__global__ __launch_bounds__(256) void prep_small(
    const float* __restrict__ wihd,   // (768,56)
    const float* __restrict__ wadj,   // (256,512)
    const float* __restrict__ wfc1,   // (56,256)
    float* __restrict__ wihdT,        // [v][j] 56x768
    float* __restrict__ wadjT,        // [f][i] 512x256
    float* __restrict__ wfc1T)        // [k][v] 256x56
{
    int idx = blockIdx.x * 256 + threadIdx.x;    // 188416 total
    if (idx < 43008) {
        int v = idx / G3, j = idx % G3;
        wihdT[idx] = wihd[j * 56 + v];
    } else if (idx < 43008 + 131072) {
        int i2 = idx - 43008;
        int f = i2 / HD, i = i2 % HD;
        wadjT[i2] = wadj[i * 512 + f];
    } else {
        int i3 = idx - 174080;
        int k = i3 / 56, v = i3 % 56;
        wfc1T[i3] = wfc1[v * HD + k];
    }
}

// gather seq rows (f16 out): seqg[(n*64+s)*192+f] = x[n, f>>2, 8s, (f>>1)&1, f&1]
__global__ __launch_bounds__(256) void gather_seq(
    const float* __restrict__ x, __half* __restrict__ seqg)
{
    int idx = blockIdx.x * 256 + threadIdx.x;    // 786432 total
    int f = idx % 192;
    int m = idx / 192;
    int n = m >> 6, s = m & 63;
    seqg[idx] = __float2half(x[n * 98304 + (f >> 2) * 2048 + s * 32 + (f & 3)]);
}

// ---------------- f16 MFMA GEMM with bias ----------------
// C[m][j] = sum_k A[m][k]*B[j][k] + bias[j]; M=4096, N=768, K in {192,512}.
// grid=(64, 12, 2); block = 4 waves; wave w computes rows m0+16w..+16,
// cols n0..n0+63 as 4 accumulators. No LDS: operands are L2-resident.
// A/B fragments use the SAME (lane-group,reg)->k formula, so the k-order
// is consistent and the dot product is exact regardless of HW k-permutation.
// C/D layout (HW-verified): col=lane&15, row=(lane>>4)*4+reg.
__global__ __launch_bounds__(256) void gemm_mfma(
    const __half* __restrict__ A,
    const __half* __restrict__ B0, const __half* __restrict__ B1,
    const float* __restrict__ bias0, const float* __restrict__ bias1,
    float* __restrict__ C0, float* __restrict__ C1, int K)
{
    const __half* B    = blockIdx.z ? B1 : B0;
    const float*  bias = blockIdx.z ? bias1 : bias0;
    float*        C    = blockIdx.z ? C1 : C0;
    const int m0 = blockIdx.x * 64;
    const int n0 = blockIdx.y * 64;
    const int w  = threadIdx.x >> 6;
    const int l  = threadIdx.x & 63;
    const int lr = l & 15;
    const int lk = (l >> 4) * 8;

    const __half* arow = A + (size_t)(m0 + w * 16 + lr) * K + lk;
    const __half* brow = B + (size_t)(n0 + lr) * K + lk;

    f32x4 acc0 = {0.f, 0.f, 0.f, 0.f};
    f32x4 acc1 = acc0, acc2 = acc0, acc3 = acc0;

#pragma unroll 2
    for (int k0 = 0; k0 < K; k0 += 32) {
        const f16x8 a  = *(const f16x8*)(arow + k0);
        const f16x8 b0 = *(const f16x8*)(brow + k0);
        const f16x8 b1 = *(const f16x8*)(brow + 16 * K + k0);
        const f16x8 b2 = *(const f16x8*)(brow + 32 * K + k0);
        const f16x8 b3 = *(const f16x8*)(brow + 48 * K + k0);
        acc0 = __builtin_amdgcn_mfma_f32_16x16x32_f16(a, b0, acc0, 0, 0, 0);
        acc1 = __builtin_amdgcn_mfma_f32_16x16x32_f16(a, b1, acc1, 0, 0, 0);
        acc2 = __builtin_amdgcn_mfma_f32_16x16x32_f16(a, b2, acc2, 0, 0, 0);
        acc3 = __builtin_amdgcn_mfma_f32_16x16x32_f16(a, b3, acc3, 0, 0, 0);
    }

    const int crow = m0 + w * 16 + (l >> 4) * 4;
    const int ccol = n0 + lr;
    float* cp = C + (size_t)crow * G3 + ccol;
    const float bb0 = bias[ccol];
    const float bb1 = bias[ccol + 16];
    const float bb2 = bias[ccol + 32];
    const float bb3 = bias[ccol + 48];
#pragma unroll
    for (int j = 0; j < 4; ++j) {
        cp[(size_t)j * G3 +  0] = acc0[j] + bb0;
        cp[(size_t)j * G3 + 16] = acc1[j] + bb1;
        cp[(size_t)j * G3 + 32] = acc2[j] + bb2;
        cp[(size_t)j * G3 + 48] = acc3[j] + bb3;
    }
}

// ---------------- fully-resident GRU scan (split-K, 512 thr, 256 VGPR) -----
// grid = 128 blocks: dir = blockIdx.x&1, n = blockIdx.x>>1.
// Thread (kh=t>>8, tr=t&255): gate rows {tr,256+tr,512+tr}, k-half kh.
// All 48 uint4 weight chunks register-resident; NO loads in the step loop.
// kh==1 half prefetches next step's gi into LDS during the gate phase.
// RESIDENCY LEDGER (r2-r7): 170/128-reg caps spill; AGPR asm parking spills;
// streamed-L2 is latency-bound; (512,1) cap=256 with demand ~230 fits.
__global__ __launch_bounds__(512, 1) void gru_scan(
    const float* __restrict__ giF, const float* __restrict__ giB,
    const uint32_t* __restrict__ wTF, const uint32_t* __restrict__ wTB,
    const float* __restrict__ bhhF, const float* __restrict__ bhhB,
    __half* __restrict__ y1, float* __restrict__ hfin, int mode)
{
    const int dir = blockIdx.x & 1;
    const int n   = blockIdx.x >> 1;
    const int t   = threadIdx.x;
    const int tr  = t & 255;
    const int kh  = t >> 8;
    const int hoff = kh * 64;        // u32 offset into h buffer
    const float* gi  = dir ? giB : giF;
    const float* bhh = dir ? bhhB : bhhF;
    const uint4* wbase = (const uint4*)(dir ? wTB : wTF) + (size_t)(kh * 16) * G3 + tr;

    __shared__ __align__(16) uint32_t h1u[2][HD / 2];  // h as f16x2, dbuf
    __shared__ float ph_r[HD], ph_z[HD], ph_n[HD];     // upper-half partials
    __shared__ float gin[2][G3];                       // gi double buffer

    L16(LRES)
    const float bhr = bhh[tr], bhz = bhh[256 + tr], bhn = bhh[512 + tr];

    const float* gbase = gi + (size_t)n * NSTEP * G3;
    const int s0 = dir ? (NSTEP - 1) : 0;
#pragma unroll
    for (int i = t; i < G3; i += 512) gin[0][i] = gbase[s0 * G3 + i];

    float h_own = 0.0f;
    if (t < HD / 2) h1u[0][t] = 0u;
    __syncthreads();

    int s = s0;
    for (int step = 0; step < NSTEP; ++step) {
        const uint32_t* hb = h1u[step & 1];
        float ar0 = 0.f, ar1 = 0.f;
        float az0 = 0.f, az1 = 0.f;
        float an0 = 0.f, an1 = 0.f;
        L16(DRES)

        if (kh) {
            ph_r[tr] = ar0 + ar1;
            ph_z[tr] = az0 + az1;
            ph_n[tr] = an0 + an1;
        }
        __syncthreads();
        const int s_nxt = dir ? (step < NSTEP - 1 ? NSTEP - 2 - step : 0)
                              : (step < NSTEP - 1 ? step + 1 : NSTEP - 1);
        if (kh == 0) {
            const float* gcur = gin[step & 1];
            const float ghr = (ar0 + ar1) + ph_r[tr] + bhr;
            const float ghz = (az0 + az1) + ph_z[tr] + bhz;
            const float ghn = (an0 + an1) + ph_n[tr] + bhn;
            const float r  = sigmf(gcur[tr] + ghr);
            const float z  = sigmf(gcur[256 + tr] + ghz);
            const float nn = tanhf(gcur[512 + tr] + r * ghn);
            const float hnew = (1.0f - z) * nn + z * h_own;
            h_own = hnew;
            const __half hh = __float2half(hnew);
            ((__half*)h1u[(step + 1) & 1])[tr] = hh;
            if (mode == 0)
                y1[(size_t)(n * NSTEP + s) * 512 + dir * HD + tr] = hh;
        } else {
            float* gnxt = gin[(step + 1) & 1];
#pragma unroll
            for (int i = tr; i < G3; i += 256)
                gnxt[i] = gbase[s_nxt * G3 + i];
        }
        s = s_nxt;
        __syncthreads();
    }
    if (mode == 1 && kh == 0)
        hfin[(size_t)(dir * NSEQ + n) * HD + tr] = h_own;
}

// ---------------- dec_h = w_adj @ [hf,hb] + b_adj ----------------
__global__ __launch_bounds__(256) void adj_kernel(
    const float* __restrict__ hfin, const float* __restrict__ wadjT,
    const float* __restrict__ badj, float* __restrict__ dech)
{
    const int n = blockIdx.x, t = threadIdx.x;
    __shared__ float comb[512];
    comb[t]      = hfin[(size_t)n * HD + t];
    comb[HD + t] = hfin[(size_t)(NSEQ + n) * HD + t];
    __syncthreads();
    float acc = badj[t];
#pragma unroll 8
    for (int f = 0; f < 512; ++f) acc += wadjT[f * HD + t] * comb[f];
    dech[n * HD + t] = acc;
}

// ---------------- decoder: 64 blocks x 768 threads, streamed weights -------
// Thread j owns gate row j: 32 coalesced uint4 loads/step from L2 (no
// residency fight -> no spill). gh/gi via LDS; gates on threads<256;
// fc1 on 448 threads (8-way split-K).
__global__ __launch_bounds__(768, 3) void decoder_kernel(
    const float* __restrict__ dech, const uint32_t* __restrict__ wTd,
    const float* __restrict__ wihdT, const float* __restrict__ bihd,
    const float* __restrict__ bhhd, const float* __restrict__ wfc1T,
    const float* __restrict__ bfc1, float* __restrict__ out)
{
    const int n = blockIdx.x, t = threadIdx.x;
    const uint4* wq = (const uint4*)wTd + t;

    __shared__ __align__(16) uint32_t h1u[2][HD / 2];
    __shared__ float ghs[G3], gis[G3];
    __shared__ float hfp[HD];
    __shared__ float inp[56];
    __shared__ float pf1[448];

    const float bi = bihd[t], bh = bhhd[t];

    float h_own = 0.0f;
    if (t < HD) {
        const float hv = dech[(size_t)n * HD + t];
        h_own = hv;
        ((__half*)h1u[0])[t] = __float2half(hv);
        hfp[t] = hv;
    }
    if (t < 56) inp[t] = 0.0f;
    __syncthreads();

    for (int step = 0; step < 6; ++step) {
        const uint32_t* hb = h1u[step & 1];
        float a0 = 0.f, a1 = 0.f;
#pragma unroll 8
        for (int q = 0; q < 32; ++q) {
            const uint4 w = wq[q * G3];
            const uint4 hp = *(const uint4*)&hb[4 * q];
            a0 = fdot2u(w.x, hp.x, a0); a1 = fdot2u(w.y, hp.y, a1);
            a0 = fdot2u(w.z, hp.z, a0); a1 = fdot2u(w.w, hp.w, a1);
        }
        float ai = bi;
#pragma unroll 8
        for (int v = 0; v < 56; ++v) ai += wihdT[v * G3 + t] * inp[v];
        ghs[t] = a0 + a1 + bh;
        gis[t] = ai;
        __syncthreads();
        if (t < HD) {
            const float r  = sigmf(gis[t] + ghs[t]);
            const float z  = sigmf(gis[HD + t] + ghs[HD + t]);
            const float nn = tanhf(gis[2 * HD + t] + r * ghs[2 * HD + t]);
            const float hnew = (1.0f - z) * nn + z * h_own;
            h_own = hnew;
            ((__half*)h1u[(step + 1) & 1])[t] = __float2half(hnew);
            hfp[t] = hnew;
        }
        __syncthreads();
        if (t < 448) {
            const int v = t >> 3, g = t & 7;
            float o = 0.f;
#pragma unroll
            for (int k2 = 0; k2 < 32; ++k2)
                o += wfc1T[(g * 32 + k2) * 56 + v] * hfp[g * 32 + k2];
            pf1[t] = o;
        }
        __syncthreads();
        if (t < 56) {
            float o = bfc1[t];
#pragma unroll
            for (int g = 0; g < 8; ++g) o += pf1[t * 8 + g];
            out[(size_t)n * 336 + step * 56 + t] = o;
            inp[t] = o;
        }
        __syncthreads();
    }
}

// ---------------------------------------------------------------------------
extern "C" void kernel_launch(void* const* d_in, const int* in_sizes, int n_in,
                              void* d_out, int out_size, void* d_ws, size_t ws_size,
                              hipStream_t stream)
{
    const float* x      = (const float*)d_in[0];
    const float* wih1f  = (const float*)d_in[1];
    const float* whh1f  = (const float*)d_in[2];
    const float* bih1f  = (const float*)d_in[3];
    const float* bhh1f  = (const float*)d_in[4];
    const float* wih1b  = (const float*)d_in[5];
    const float* whh1b  = (const float*)d_in[6];
    const float* bih1b  = (const float*)d_in[7];
    const float* bhh1b  = (const float*)d_in[8];
    const float* wih2f  = (const float*)d_in[9];
    const float* whh2f  = (const float*)d_in[10];
    const float* bih2f  = (const float*)d_in[11];
    const float* bhh2f  = (const float*)d_in[12];
    const float* wih2b  = (const float*)d_in[13];
    const float* whh2b  = (const float*)d_in[14];
    const float* bih2b  = (const float*)d_in[15];
    const float* bhh2b  = (const float*)d_in[16];
    const float* wihd   = (const float*)d_in[17];
    const float* whhd   = (const float*)d_in[18];
    const float* bihd   = (const float*)d_in[19];
    const float* bhhd   = (const float*)d_in[20];
    const float* wfc1   = (const float*)d_in[21];
    const float* bfc1   = (const float*)d_in[22];
    const float* wadj   = (const float*)d_in[23];
    const float* badj   = (const float*)d_in[24];

    float* ws = (float*)d_ws;
    __half*   seqg_h  = (__half*)(ws + 0);           // 786432 f16
    float*    gi_f    = ws + 393216;                 // 3145728
    float*    gi_b    = ws + 3538944;                // 3145728
    __half*   y1h     = (__half*)(ws + 6684672);     // 2097152 f16
    float*    hfin    = ws + 7733248;                // 32768
    float*    dech    = ws + 7766016;                // 16384
    uint32_t* wt1f    = (uint32_t*)(ws + 7782400);   // 98304 each
    uint32_t* wt1b    = (uint32_t*)(ws + 7880704);
    uint32_t* wt2f    = (uint32_t*)(ws + 7979008);
    uint32_t* wt2b    = (uint32_t*)(ws + 8077312);
    uint32_t* wtd     = (uint32_t*)(ws + 8175616);
    __half*   wih1f_h = (__half*)(ws + 8273920);     // 147456 f16
    __half*   wih1b_h = (__half*)(ws + 8347648);
    __half*   wih2f_h = (__half*)(ws + 8421376);     // 393216 f16
    __half*   wih2b_h = (__half*)(ws + 8617984);
    float*    wihdT   = ws + 8814592;                // 43008
    float*    wadjT   = ws + 8857600;                // 131072
    float*    wfc1T   = ws + 8988672;                // 14336 -> end 9003008 fl

    pack_whhT<<<dim3(96, 5), 256, 0, stream>>>(
        whh1f, whh1b, whh2f, whh2b, whhd, wt1f, wt1b, wt2f, wt2b, wtd);
    pack_wih<<<dim3(384, 4), 256, 0, stream>>>(
        wih1f, wih1b, wih2f, wih2b, wih1f_h, wih1b_h, wih2f_h, wih2b_h);
    prep_small<<<736, 256, 0, stream>>>(wihd, wadj, wfc1, wihdT, wadjT, wfc1T);
    gather_seq<<<3072, 256, 0, stream>>>(x, seqg_h);

    // layer 1
    gemm_mfma<<<dim3(64, 12, 2), 256, 0, stream>>>(
        seqg_h, wih1f_h, wih1b_h, bih1f, bih1b, gi_f, gi_b, 192);
    gru_scan<<<128, 512, 0, stream>>>(
        gi_f, gi_b, wt1f, wt1b, bhh1f, bhh1b, y1h, hfin, 0);

    // layer 2 (gi buffers reused; stream order serializes)
    gemm_mfma<<<dim3(64, 12, 2), 256, 0, stream>>>(
        y1h, wih2f_h, wih2b_h, bih2f, bih2b, gi_f, gi_b, 512);
    gru_scan<<<128, 512, 0, stream>>>(
        gi_f, gi_b, wt2f, wt2b, bhh2f, bhh2b, y1h, hfin, 1);

    // decoder head
    adj_kernel<<<64, 256, 0, stream>>>(hfin, wadjT, badj, dech);
    decoder_kernel<<<64, 768, 0, stream>>>(
        dech, wtd, wihdT, bihd, bhhd, wfc1T, bfc1, (float*)d_out);
}